// Round 5
// baseline (286.609 us; speedup 1.0000x reference)
//
#include <hip/hip_runtime.h>
#include <stdint.h>
#include <stddef.h>

// Causal GQA prefill attention, MI355X gfx950.
// Round 5: deterministic staging — prepacked bf16 tile image is loaded with
// plain global_load_dwordx4 into registers (prefetched one step ahead) and
// committed with ds_write_b128; synchronization is pure lgkmcnt/s_barrier
// (no global_load_lds DMA, whose barrier-drain was the prime suspect for the
// r4 tripwire nondeterminism). Keeps r4's wins: 32 q-rows/wave (each LDS K/V
// read feeds two MFMAs), static-max exp2 softmax (exact: scores can't
// overflow fp32 exp2), pair-fold load balance, zero-conflict tile layout.
//
// Verified (r0-r3): S^T = K*Q^T via mfma_16x16x32_bf16; its C-layout
// (row=key=quad*4+r, col=q=l15) equals the A-operand layout of
// mfma_16x16x16bf16_1k, so softmaxed P feeds PV straight from registers.
//
// Tile image (32 KB per 64-key tile; LDS image identical):
//   K-part (16384 B): chunk c 0..15, key r 0..63: [c*1024 + r*16] = K[r][c*8..+7]
//   V-part (16384 B): unit u 0..15, d 0..127: [16384 + u*1024 + d*8] = V^T bf16x4

#define S_LEN   2048
#define HQ      32
#define HKV     8
#define DH      128
#define QSTRIDE (HQ*DH)
#define KSTRIDE (HKV*DH)
// (1/sqrt(128)) * log2(e): softmax in exp2 space
#define SCALE_L2 0.12751139830213113f

#define KTILE      64
#define NTILES     (S_LEN/KTILE)          // 32
#define TILE_ELEMS 16384                  // bf16 elems per tile image (32 KB)
#define KPART      8192                   // elems in K-part

typedef __bf16 bf16;
typedef short        s16x4 __attribute__((ext_vector_type(4)));
typedef short        s16x8 __attribute__((ext_vector_type(8)));
typedef float        f32x4 __attribute__((ext_vector_type(4)));
typedef unsigned int u32x2 __attribute__((ext_vector_type(2)));
typedef unsigned int u32x4 __attribute__((ext_vector_type(4)));

__device__ __forceinline__ unsigned int pk2(float a, float b) {
  union { bf16 h[2]; unsigned int u; } x;
  x.h[0] = (bf16)a; x.h[1] = (bf16)b;    // fptrunc = RNE
  return x.u;
}

// ---------------- pre-pass: fp32 K/V -> bf16 swizzled tile images ----------
// Build the 32 KB image in LDS (scattered, cheap), then write coalesced.
__global__ __launch_bounds__(256)
void prepack(const float* __restrict__ kg, const float* __restrict__ vg,
             bf16* __restrict__ ws) {
  __shared__ bf16 tile[TILE_ELEMS];
  const int t   = blockIdx.x;            // tile 0..31
  const int hkv = blockIdx.y;
  const int b   = blockIdx.z;
  const int tid = threadIdx.x;

  // K-part: thread handles row key=tid>>2, d-cols (tid&3)*32..+31
  {
    const int key = tid >> 2, cg = tid & 3;
    const float* kp = kg + (size_t)(b*S_LEN + t*KTILE + key)*KSTRIDE
                         + hkv*DH + cg*32;
    float4 x[8];
#pragma unroll
    for (int i = 0; i < 8; ++i) x[i] = ((const float4*)kp)[i];
#pragma unroll
    for (int ii = 0; ii < 4; ++ii) {
      const int chunk = cg*4 + ii;
      u32x4 w;
      w[0] = pk2(x[2*ii].x,   x[2*ii].y);   w[1] = pk2(x[2*ii].z,   x[2*ii].w);
      w[2] = pk2(x[2*ii+1].x, x[2*ii+1].y); w[3] = pk2(x[2*ii+1].z, x[2*ii+1].w);
      *(u32x4*)(tile + chunk*512 + key*8) = w;
    }
  }
  // V-part: thread handles keys 2vj,2vj+1, d-range dg*16..+15
  {
    const int vj = tid & 31, dg = tid >> 5;
    const float* v0 = vg + (size_t)(b*S_LEN + t*KTILE + 2*vj)*KSTRIDE
                         + hkv*DH + dg*16;
    const float* v1 = v0 + KSTRIDE;
    float4 a[4], c[4];
#pragma unroll
    for (int i = 0; i < 4; ++i) { a[i] = ((const float4*)v0)[i];
                                  c[i] = ((const float4*)v1)[i]; }
    const float* f0 = (const float*)a;
    const float* f1 = (const float*)c;
    const int unit = vj >> 1, slot = (vj & 1)*2;
#pragma unroll
    for (int i = 0; i < 16; ++i) {
      const int d = dg*16 + i;
      *(unsigned int*)(tile + KPART + unit*512 + d*4 + slot) = pk2(f0[i], f1[i]);
    }
  }
  __syncthreads();
  // coalesced image write: 2048 x 16B, 8 per thread
  bf16* img = ws + (size_t)((b*HKV + hkv)*NTILES + t)*TILE_ELEMS;
  const u32x4* s4 = (const u32x4*)tile;
  u32x4*       d4 = (u32x4*)img;
#pragma unroll
  for (int i = 0; i < 8; ++i) d4[i*256 + tid] = s4[i*256 + tid];
  __threadfence();   // device-scope release insurance for cross-kernel handoff
}

// ---------------- main kernel ----------------------------------------------
template<bool USE_WS>
__global__ __launch_bounds__(256, 2)
void attn_fwd(const float* __restrict__ qg, const float* __restrict__ kg,
              const float* __restrict__ vg, float* __restrict__ og,
              const bf16* __restrict__ ws) {
  __shared__ bf16 smem[2*TILE_ELEMS];    // 65,536 B, double-buffered

  const int tid   = threadIdx.x;
  const int lane  = tid & 63;
  const int wave  = tid >> 6;            // 4 waves/block
  const int l15   = lane & 15;
  const int quad  = lane >> 4;
  const int pairp = blockIdx.x;          // 0..7
  const int h     = blockIdx.y;          // 0..31
  const int b     = blockIdx.z;          // 0..1
  const int hkv   = h >> 2;

  const bf16* imgs = USE_WS ? ws + (size_t)(b*HKV + hkv)*NTILES*TILE_ELEMS
                            : nullptr;

  // ---- staging (USE_WS=true): registers, one full step of prefetch ----
  u32x4 sreg[8];
  auto load_img = [&](int t) {           // coalesced: 2048 x 16B, 8/thread
    const u32x4* timg = (const u32x4*)(imgs + (size_t)t*TILE_ELEMS);
#pragma unroll
    for (int i = 0; i < 8; ++i) sreg[i] = timg[i*256 + tid];
  };
  auto store_img = [&](int bi) {         // stride-1 b128: conflict-free
    u32x4* lb = (u32x4*)(smem + bi*TILE_ELEMS);
#pragma unroll
    for (int i = 0; i < 8; ++i) lb[i*256 + tid] = sreg[i];
  };

  // ---- fallback staging roles (USE_WS=false): cvt in-kernel ----
  const int fk_key = tid >> 2, fk_cg = tid & 3;
  const int fv_j   = tid & 31, fv_dg = tid >> 5;
  float4 fkx[8], fvx[8];

  auto load_regs = [&](int t) {
    const float* kp = kg + (size_t)(b*S_LEN + t*KTILE + fk_key)*KSTRIDE
                         + hkv*DH + fk_cg*32;
#pragma unroll
    for (int i = 0; i < 8; ++i) fkx[i] = ((const float4*)kp)[i];
    const float* v0 = vg + (size_t)(b*S_LEN + t*KTILE + 2*fv_j)*KSTRIDE
                         + hkv*DH + fv_dg*16;
    const float* v1 = v0 + KSTRIDE;
#pragma unroll
    for (int i = 0; i < 4; ++i) { fvx[i]   = ((const float4*)v0)[i];
                                  fvx[4+i] = ((const float4*)v1)[i]; }
  };
  auto store_tile = [&](int bi) {
    bf16* kb = smem + bi*TILE_ELEMS;
#pragma unroll
    for (int ii = 0; ii < 4; ++ii) {
      const int chunk = fk_cg*4 + ii;
      u32x4 w;
      w[0] = pk2(fkx[2*ii].x,   fkx[2*ii].y);   w[1] = pk2(fkx[2*ii].z,   fkx[2*ii].w);
      w[2] = pk2(fkx[2*ii+1].x, fkx[2*ii+1].y); w[3] = pk2(fkx[2*ii+1].z, fkx[2*ii+1].w);
      *(u32x4*)(kb + chunk*512 + fk_key*8) = w;
    }
    bf16* vb = kb + KPART;
    const float* f0 = (const float*)&fvx[0];
    const float* f1 = (const float*)&fvx[4];
    const int unit = fv_j >> 1, slot = (fv_j & 1)*2;
#pragma unroll
    for (int i = 0; i < 16; ++i) {
      const int d = fv_dg*16 + i;
      *(unsigned int*)(vb + unit*512 + d*4 + slot) = pk2(f0[i], f1[i]);
    }
  };

  f32x4 oacc[2][8];                      // [q subtile][d tile], C-layout
  float l_run[2];
  u32x4 qf[2][4];

  const int qbs[2] = { pairp, 15 - pairp };     // balanced: 34 steps total
  if (USE_WS) load_img(0); else load_regs(0);

  int gs = 0;                                   // flat step counter
#pragma unroll 1
  for (int item = 0; item < 2; ++item) {
    const int qblk = qbs[item];
    const int qw   = qblk*128 + wave*32;        // this wave's 32 q-rows
    const int nst  = qblk*2 + 2;

    // Q fragments (B-operand of S^T = K*Q^T), scale*log2e folded in
#pragma unroll
    for (int nt = 0; nt < 2; ++nt) {
      const float* qp = qg + (size_t)(b*S_LEN + qw + nt*16 + l15)*QSTRIDE
                           + h*DH + quad*8;
#pragma unroll
      for (int c = 0; c < 4; ++c) {
        const float4 a4 = ((const float4*)(qp + c*32))[0];
        const float4 b4 = ((const float4*)(qp + c*32))[1];
        u32x4 w;
        w[0] = pk2(a4.x*SCALE_L2, a4.y*SCALE_L2);
        w[1] = pk2(a4.z*SCALE_L2, a4.w*SCALE_L2);
        w[2] = pk2(b4.x*SCALE_L2, b4.y*SCALE_L2);
        w[3] = pk2(b4.z*SCALE_L2, b4.w*SCALE_L2);
        qf[nt][c] = w;
      }
    }
#pragma unroll
    for (int nt = 0; nt < 2; ++nt)
#pragma unroll
      for (int nd = 0; nd < 8; ++nd)
        oacc[nt][nd] = (f32x4){0.f, 0.f, 0.f, 0.f};
    l_run[0] = l_run[1] = 0.f;

#pragma unroll 1
    for (int i = 0; i < nst; ++i, ++gs) {
      const int k0  = i*KTILE;
      const int buf = gs & 1;
      // commit prefetched tile `gs` to LDS, then make it visible
      if (USE_WS) store_img(buf); else store_tile(buf);
      __syncthreads();                         // lgkmcnt(0)+barrier: airtight
      const bool more  = (i + 1 < nst);
      const bool cross = (!more) && (item == 0);
      if (USE_WS) {
        if (more)       load_img(i + 1);       // overlaps compute below
        else if (cross) load_img(0);
      } else {
        if (more)       load_regs(i + 1);
        else if (cross) load_regs(0);
      }

      if (k0 <= qw + 31) {                     // wave-uniform causal skip
        const bf16* kb = smem + buf*TILE_ELEMS;
        const bf16* vb = kb + KPART;

        // ---- S^T = K_tile * Q^T : 4 key-subtiles x 2 q-subtiles ----
        // ONE LDS read feeds TWO MFMAs (the point of 32 q/wave).
        f32x4 sacc[4][2];
#pragma unroll
        for (int mt = 0; mt < 4; ++mt)
#pragma unroll
          for (int nt = 0; nt < 2; ++nt)
            sacc[mt][nt] = (f32x4){0.f, 0.f, 0.f, 0.f};
#pragma unroll
        for (int c = 0; c < 4; ++c)
#pragma unroll
          for (int mt = 0; mt < 4; ++mt) {
            const u32x4 af = *(const u32x4*)(kb + (c*4 + quad)*512
                                                + (mt*16 + l15)*8);
            sacc[mt][0] = __builtin_amdgcn_mfma_f32_16x16x32_bf16(
                __builtin_bit_cast(s16x8, af), __builtin_bit_cast(s16x8, qf[0][c]),
                sacc[mt][0], 0, 0, 0);
            sacc[mt][1] = __builtin_amdgcn_mfma_f32_16x16x32_bf16(
                __builtin_bit_cast(s16x8, af), __builtin_bit_cast(s16x8, qf[1][c]),
                sacc[mt][1], 0, 0, 0);
          }

        // ---- static-max softmax in exp2 space (M = 0, exact) ----
        const bool needmask = (k0 + KTILE - 1 > qw);   // wave-uniform
        s16x4 pa[4][2];
#pragma unroll
        for (int nt = 0; nt < 2; ++nt) {
          const int qgl = qw + nt*16 + l15;
          float rsum = 0.f;
#pragma unroll
          for (int mt = 0; mt < 4; ++mt)
#pragma unroll
            for (int r = 0; r < 4; ++r) {
              float sv = sacc[mt][nt][r];
              if (needmask) {
                const int key = k0 + mt*16 + quad*4 + r;
                sv = (key <= qgl) ? sv : -3e38f;
              }
              const float e = __builtin_amdgcn_exp2f(sv);
              sacc[mt][nt][r] = e;
              rsum += e;
            }
          rsum += __shfl_xor(rsum, 16);
          rsum += __shfl_xor(rsum, 32);
          l_run[nt] += rsum;
#pragma unroll
          for (int mt = 0; mt < 4; ++mt) {     // P already in A-layout
            union { bf16 hh[4]; s16x4 s; } u;
#pragma unroll
            for (int r = 0; r < 4; ++r) u.hh[r] = (bf16)sacc[mt][nt][r];
            pa[mt][nt] = u.s;
          }
        }

        // ---- O += P * V  (one LDS read feeds TWO MFMAs) ----
#pragma unroll
        for (int kt = 0; kt < 4; ++kt)
#pragma unroll
          for (int nd = 0; nd < 8; ++nd) {
            const s16x4 bv = *(const s16x4*)(vb + (kt*4 + quad)*512
                                                + (nd*16 + l15)*4);
            oacc[0][nd] = __builtin_amdgcn_mfma_f32_16x16x16bf16_1k(
                pa[kt][0], bv, oacc[0][nd], 0, 0, 0);
            oacc[1][nd] = __builtin_amdgcn_mfma_f32_16x16x16bf16_1k(
                pa[kt][1], bv, oacc[1][nd], 0, 0, 0);
          }
      }
    }

    // ---- epilogue: O / l, fp32 store ----
#pragma unroll
    for (int nt = 0; nt < 2; ++nt)
#pragma unroll
      for (int r = 0; r < 4; ++r) {
        const float li  = __shfl(l_run[nt], (lane & 48) | (quad*4 + r));
        const float inv = 1.0f / li;
        const size_t base = (size_t)(b*S_LEN + qw + nt*16 + quad*4 + r)*QSTRIDE
                          + h*DH + l15;
#pragma unroll
        for (int nd = 0; nd < 8; ++nd)
          og[base + nd*16] = oacc[nt][nd][r] * inv;
      }
  }
}

extern "C" void kernel_launch(void* const* d_in, const int* in_sizes, int n_in,
                              void* d_out, int out_size, void* d_ws, size_t ws_size,
                              hipStream_t stream) {
  const float* q = (const float*)d_in[0];
  const float* k = (const float*)d_in[1];
  const float* v = (const float*)d_in[2];
  float* out = (float*)d_out;
  const size_t need = (size_t)2*HKV*NTILES*TILE_ELEMS*sizeof(bf16); // 16.78 MB
  dim3 grid(8, HQ, 2);       // 8 balanced pairs x 32 heads x 2 batches
  dim3 block(256);
  if (ws_size >= need) {
    bf16* ws = (bf16*)d_ws;
    prepack<<<dim3(NTILES, HKV, 2), 256, 0, stream>>>(k, v, ws);
    attn_fwd<true><<<grid, block, 0, stream>>>(q, k, v, out, ws);
  } else {
    attn_fwd<false><<<grid, block, 0, stream>>>(q, k, v, out, nullptr);
  }
}